// Round 11
// baseline (249.206 us; speedup 1.0000x reference)
//
#include <hip/hip_runtime.h>

typedef __attribute__((ext_vector_type(8))) __bf16 bf16x8;
typedef __attribute__((ext_vector_type(8))) unsigned short u16x8;
typedef __attribute__((ext_vector_type(4))) unsigned short u16x4;
typedef __attribute__((ext_vector_type(4))) float f32x4;

#define N_LOCI   59412
#define T_DIM    500
#define T_PAD    512
#define N_ENC    200
#define KL       29696
#define KR       29716
#define J_PAD    59648
#define G1_S     58      // split-K chunks per compartment (58*512 >= K)

__device__ __forceinline__ unsigned short cvt1(float x) {
    __bf16 h = (__bf16)x;
    return __builtin_bit_cast(unsigned short, h);
}
__device__ __forceinline__ float bf2f(unsigned short h) {
    return __uint_as_float(((unsigned)h) << 16);
}
__device__ __forceinline__ f32x4 mfma16(u16x8 a, u16x8 b, f32x4 c) {
    return __builtin_amdgcn_mfma_f32_16x16x32_bf16(
        __builtin_bit_cast(bf16x8, a), __builtin_bit_cast(bf16x8, b), c, 0, 0, 0);
}

// ---------------------------------------------------------------------------
// K0: stream X f32 -> raw bf16 Xb [J_PAD][512] (rows>=N_LOCI and cols>=500
// zeroed) + xstat=(mu, 1/||xc||). One wave per row, 4 rows per wave.
// ---------------------------------------------------------------------------
__global__ __launch_bounds__(256) void k0_xraw(const float* __restrict__ X,
                                               unsigned short* __restrict__ Xb,
                                               float2* __restrict__ xstat) {
    const int w    = threadIdx.x >> 6;
    const int lane = threadIdx.x & 63;
    const int base = blockIdx.x * 16 + w * 4;
    for (int i = 0; i < 4; ++i) {
        const int row = base + i;
        unsigned short* out = Xb + (size_t)row * T_PAD;
        if (row >= N_LOCI) {
            u16x4 z = {0, 0, 0, 0};
            *(u16x4*)(out + lane * 4) = z;
            *(u16x4*)(out + (lane + 64) * 4) = z;
            if (lane == 0) xstat[row] = make_float2(0.0f, 0.0f);
            continue;
        }
        const float4* xr = (const float4*)(X + (size_t)row * T_DIM);
        float4 v1 = xr[lane];
        float4 v2 = make_float4(0.f, 0.f, 0.f, 0.f);
        const bool has2 = (lane + 64) < 125;
        if (has2) v2 = xr[lane + 64];
        float s = v1.x + v1.y + v1.z + v1.w + v2.x + v2.y + v2.z + v2.w;
        float q = v1.x * v1.x + v1.y * v1.y + v1.z * v1.z + v1.w * v1.w
                + v2.x * v2.x + v2.y * v2.y + v2.z * v2.z + v2.w * v2.w;
        #pragma unroll
        for (int off = 32; off; off >>= 1) {
            s += __shfl_xor(s, off);
            q += __shfl_xor(q, off);
        }
        u16x4 w1, w2 = {0, 0, 0, 0};
        w1[0] = cvt1(v1.x); w1[1] = cvt1(v1.y); w1[2] = cvt1(v1.z); w1[3] = cvt1(v1.w);
        if (has2) {
            w2[0] = cvt1(v2.x); w2[1] = cvt1(v2.y); w2[2] = cvt1(v2.z); w2[3] = cvt1(v2.w);
        }
        *(u16x4*)(out + lane * 4) = w1;
        *(u16x4*)(out + (lane + 64) * 4) = w2;
        if (lane == 0) {
            const float mu = s * (1.0f / 500.0f);
            xstat[row] = make_float2(mu, rsqrtf(q - 500.0f * mu * mu));
        }
    }
}

// ---------------------------------------------------------------------------
// K2: bf16 partials P16[g][200][512] of A = W_c @ X_slice (RAW). B side
// reads bf16 Xb. Tile M=128 x N=128, BK=64, 256 thr (4 waves 2x2, wave
// 64x64), 32 KB LDS. Swizzles: A key (row&7)<<3, B key ((nl^(nl>>3))&7)<<3.
// Slot-major grid d = slot*128 + g: all 8 slots of chunk g on XCD g%8.
// ---------------------------------------------------------------------------
__global__ __launch_bounds__(256) void k2_gemm1(const unsigned short* __restrict__ Xb,
                                                const float* __restrict__ WL,
                                                const float* __restrict__ WR,
                                                unsigned short* __restrict__ P16) {
    const int d = blockIdx.x;
    const int g = d & 127;
    if (g >= 2 * G1_S) return;
    const int slot = d >> 7;       // 0..7
    const int mt = slot >> 2;      // 0..1
    const int nt = slot & 3;       // 0..3
    const int sc   = g >> 1;       // 0..57
    const int comp = g & 1;
    const int K      = comp ? KR : KL;
    const float* W   = comp ? WR : WL;
    const int xbase  = comp ? KL : 0;
    const int m0 = mt * 128;
    const int n0 = nt * 128;

    __shared__ unsigned short As[128 * 64];   // 16 KB
    __shared__ unsigned short Bs[128 * 64];   // 16 KB

    const int t = threadIdx.x, lane = t & 63, wid = t >> 6;
    const int wm = wid >> 1, wn = wid & 1;
    const int lr = lane & 15, lg = lane >> 4;

    f32x4 acc[4][4];
    #pragma unroll
    for (int i = 0; i < 4; ++i)
        #pragma unroll
        for (int j = 0; j < 4; ++j) {
            f32x4 z = {0.f, 0.f, 0.f, 0.f};
            acc[i][j] = z;
        }

    const int nsteps = (comp && sc == G1_S - 1) ? 9 : 8;

    // A staging: row am (0..127), 32-k segment aseg
    const int am = t >> 1, aseg = t & 1;
    const int arow = (m0 + am < N_ENC) ? (m0 + am) : (N_ENC - 1);
    const float* wrow = W + (size_t)arow * K;
    const int akey = (am & 7) << 3;
    // B staging: k-quad kq (0..15 -> 4 rows), col thread tc (0..15 -> 8 cols)
    const int kq = t >> 4, tc = t & 15;

    u16x8 ha[4];
    u16x8 hb4[4];

    auto load_tiles = [&](int st) {
        const int k0 = sc * 512 + st * 64;
        // ---- A: 32 k per thread (f32 -> bf16) ----
        {
            const int kb = k0 + aseg * 32;
            float av[32];
            if (kb + 31 < K) {
                #pragma unroll
                for (int f = 0; f < 8; ++f) {
                    const float4 v = *(const float4*)(wrow + kb + f * 4);
                    av[f * 4 + 0] = v.x; av[f * 4 + 1] = v.y;
                    av[f * 4 + 2] = v.z; av[f * 4 + 3] = v.w;
                }
            } else {
                #pragma unroll
                for (int j = 0; j < 32; ++j)
                    av[j] = (kb + j < K) ? wrow[kb + j] : 0.0f;
            }
            #pragma unroll
            for (int q = 0; q < 4; ++q) {
                u16x8 hh;
                #pragma unroll
                for (int j = 0; j < 8; ++j) hh[j] = cvt1(av[q * 8 + j]);
                ha[q] = hh;
            }
        }
        // ---- B: 4 k-rows x 8 cols per thread, straight bf16 loads ----
        #pragma unroll
        for (int r = 0; r < 4; ++r) {
            const int krel = k0 + kq * 4 + r;
            if (krel < K) {
                hb4[r] = *(const u16x8*)(Xb + (size_t)(xbase + krel) * T_PAD + n0 + tc * 8);
            } else {
                u16x8 z = {0, 0, 0, 0, 0, 0, 0, 0};
                hb4[r] = z;
            }
        }
    };

    auto write_stage = [&]() {
        #pragma unroll
        for (int q = 0; q < 4; ++q)
            *(u16x8*)&As[am * 64 + ((aseg * 32 + q * 8) ^ akey)] = ha[q];
        #pragma unroll
        for (int j = 0; j < 8; ++j) {
            const int nl = tc * 8 + j;
            const int key = ((nl ^ (nl >> 3)) & 7) << 3;
            u16x4 w4 = { hb4[0][j], hb4[1][j], hb4[2][j], hb4[3][j] };
            *(u16x4*)&Bs[nl * 64 + ((kq * 4) ^ key)] = w4;
        }
    };

    load_tiles(0);
    for (int st = 0; st < nsteps; ++st) {
        write_stage();
        __syncthreads();
        if (st + 1 < nsteps) load_tiles(st + 1);   // loads in flight during MFMA
        #pragma unroll
        for (int h = 0; h < 2; ++h) {
            u16x8 af[4], bf[4];
            #pragma unroll
            for (int mf = 0; mf < 4; ++mf) {
                const int m = wm * 64 + mf * 16 + lr;
                af[mf] = *(const u16x8*)&As[m * 64 + ((h * 32 + lg * 8) ^ ((m & 7) << 3))];
            }
            #pragma unroll
            for (int nf = 0; nf < 4; ++nf) {
                const int nl = wn * 64 + nf * 16 + lr;
                const int key = ((nl ^ (nl >> 3)) & 7) << 3;
                bf[nf] = *(const u16x8*)&Bs[nl * 64 + ((h * 32 + lg * 8) ^ key)];
            }
            #pragma unroll
            for (int mf = 0; mf < 4; ++mf)
                #pragma unroll
                for (int nf = 0; nf < 4; ++nf)
                    acc[mf][nf] = mfma16(af[mf], bf[nf], acc[mf][nf]);
        }
        __syncthreads();
    }

    unsigned short* Pb = P16 + (size_t)g * (200 * 512);
    #pragma unroll
    for (int mf = 0; mf < 4; ++mf)
        #pragma unroll
        for (int rr = 0; rr < 4; ++rr) {
            const int m = m0 + wm * 64 + mf * 16 + lg * 4 + rr;
            if (m < N_ENC) {
                #pragma unroll
                for (int nf = 0; nf < 4; ++nf) {
                    const int n = n0 + wn * 64 + nf * 16 + lr;
                    Pb[(size_t)m * 512 + n] = cvt1(acc[mf][nf][rr]);
                }
            }
        }
}

// ---------------------------------------------------------------------------
// K3: sum bf16 split-K partials (slice = s2*2 + comp) -> raw A row;
// store RAW bf16 Ab [512][512] (pad zero) + astat=(mu, 1/||Ac||).
// ---------------------------------------------------------------------------
__global__ __launch_bounds__(256) void k3_astats(const unsigned short* __restrict__ P16,
                                                 unsigned short* __restrict__ Ab,
                                                 float2* __restrict__ astat) {
    const int r = blockIdx.x;   // 0..511
    const int t = threadIdx.x;  // 0..255
    unsigned short* out = Ab + (size_t)r * T_PAD;
    if (r >= 2 * N_ENC) {
        out[t] = 0; out[t + 256] = 0;
        if (t == 0) astat[r] = make_float2(0.0f, 0.0f);
        return;
    }
    const int comp = (r >= N_ENC) ? 1 : 0;
    const int m = r - comp * N_ENC;
    float a1 = 0.0f, a2 = 0.0f;
    for (int s2 = 0; s2 < G1_S; ++s2) {
        const unsigned short* Pb = P16 + ((size_t)(s2 * 2 + comp) * 200 + m) * 512;
        a1 += bf2f(Pb[t]);
        a2 += bf2f(Pb[t + 256]);
    }
    const bool v2ok = (t + 256) < T_DIM;
    const float b2 = v2ok ? a2 : 0.0f;
    float s = a1 + b2;
    float q = a1 * a1 + b2 * b2;
    #pragma unroll
    for (int off = 32; off; off >>= 1) {
        s += __shfl_xor(s, off);
        q += __shfl_xor(q, off);
    }
    __shared__ float ls[4], lq[4];
    if ((t & 63) == 0) { ls[t >> 6] = s; lq[t >> 6] = q; }
    __syncthreads();
    const float S = ls[0] + ls[1] + ls[2] + ls[3];
    const float Q = lq[0] + lq[1] + lq[2] + lq[3];
    const float mean = S * (1.0f / 500.0f);
    const float iv   = rsqrtf(Q - 500.0f * mean * mean);
    out[t] = cvt1(a1);
    out[t + 256] = v2ok ? cvt1(a2) : (unsigned short)0;
    if (t == 0) astat[r] = make_float2(mean, iv);
}

// ---------------------------------------------------------------------------
// K4: G = Ab @ Xb^T (raw), epilogue C = (G - 500*muA*muX)*invA*invX.
// LDS-FREE: both operands are [row][k] bf16 with k contiguous, so every MFMA
// fragment (lane lr holds 8 k at row +lr, k base lg*8) is a direct 16B global
// load. A 64-lane frag load = 16 full 64B lines (perfectly coalesced); Ab is
// 512 KB (L2-resident) and the Xb j-slice (128 KB) is shared by the 4 mt
// partner blocks on the same XCD. No barriers -> pure ILP; no LDS -> VGPR-
// limited occupancy (~4 blocks/CU).
// Tile 128m x 128j, 256 thr (4 waves 2x2, wave 64x64), 16 k-steps of 32.
// Grid 1888 XCD-grouped: jt=(d>>5)*8+(d&7) (<465), mt=(d>>3)&3.
// ---------------------------------------------------------------------------
__global__ __launch_bounds__(256) void k4_gemm2(const unsigned short* __restrict__ Ab,
                                                const unsigned short* __restrict__ Xb,
                                                const float2* __restrict__ astat,
                                                const float2* __restrict__ xstat,
                                                float* __restrict__ C) {
    const int d  = blockIdx.x;
    const int jt = (d >> 5) * 8 + (d & 7);
    if (jt >= 465) return;
    const int mt = (d >> 3) & 3;
    const int j0 = jt * 128;
    const int m0 = mt * 128;

    const int t = threadIdx.x, lane = t & 63, wid = t >> 6;
    const int wm = wid >> 1, wn = wid & 1;
    const int lg = lane >> 4, lr = lane & 15;

    f32x4 acc[4][4];
    #pragma unroll
    for (int i = 0; i < 4; ++i)
        #pragma unroll
        for (int j = 0; j < 4; ++j) {
            f32x4 z = {0.f, 0.f, 0.f, 0.f};
            acc[i][j] = z;
        }

    const unsigned short* ap[4];
    const unsigned short* bp[4];
    #pragma unroll
    for (int mf = 0; mf < 4; ++mf)
        ap[mf] = Ab + (size_t)(m0 + wm * 64 + mf * 16 + lr) * T_PAD + lg * 8;
    #pragma unroll
    for (int nf = 0; nf < 4; ++nf)
        bp[nf] = Xb + (size_t)(j0 + wn * 64 + nf * 16 + lr) * T_PAD + lg * 8;

    #pragma unroll 2
    for (int k0 = 0; k0 < 512; k0 += 32) {
        u16x8 af[4], bf[4];
        #pragma unroll
        for (int mf = 0; mf < 4; ++mf) af[mf] = *(const u16x8*)(ap[mf] + k0);
        #pragma unroll
        for (int nf = 0; nf < 4; ++nf) bf[nf] = *(const u16x8*)(bp[nf] + k0);
        #pragma unroll
        for (int mf = 0; mf < 4; ++mf)
            #pragma unroll
            for (int nf = 0; nf < 4; ++nf)
                acc[mf][nf] = mfma16(af[mf], bf[nf], acc[mf][nf]);
    }

    #pragma unroll
    for (int mf = 0; mf < 4; ++mf) {
        const int row = m0 + wm * 64 + mf * 16 + lg * 4;
        #pragma unroll
        for (int nf = 0; nf < 4; ++nf) {
            const int col = j0 + wn * 64 + nf * 16 + lr;
            if (col < N_LOCI) {
                const float2 xs = xstat[col];
                #pragma unroll
                for (int rr = 0; rr < 4; ++rr) {
                    if (row + rr < 2 * N_ENC) {
                        const float2 as = astat[row + rr];
                        C[(size_t)(row + rr) * N_LOCI + col] =
                            (acc[mf][nf][rr] - 500.0f * as.x * xs.x) * as.y * xs.y;
                    }
                }
            }
        }
    }
}

// ---------------------------------------------------------------------------
extern "C" void kernel_launch(void* const* d_in, const int* in_sizes, int n_in,
                              void* d_out, int out_size, void* d_ws, size_t ws_size,
                              hipStream_t stream) {
    const float* X  = (const float*)d_in[0];
    const float* WL = (const float*)d_in[1];
    const float* WR = (const float*)d_in[2];
    float* C = (float*)d_out;

    // workspace (total ~85.8 MB):
    //   Xb    u16 [59648][512]     : 61,079,552 B
    //   P16   u16 [116][200][512]  : 23,756,800 B
    //   Ab    u16 [512][512]       :    524,288 B
    //   astat f32x2 [512]          :      4,096 B
    //   xstat f32x2 [59648]        :    477,184 B
    char* w = (char*)d_ws;
    unsigned short* Xb  = (unsigned short*)w;  w += (size_t)J_PAD * T_PAD * 2;
    unsigned short* P16 = (unsigned short*)w;  w += (size_t)2 * G1_S * 200 * 512 * 2;
    unsigned short* Ab  = (unsigned short*)w;  w += (size_t)512 * 512 * 2;
    float2* astat = (float2*)w;                w += (size_t)512 * 8;
    float2* xstat = (float2*)w;

    k0_xraw<<<dim3(J_PAD / 16), dim3(256), 0, stream>>>(X, Xb, xstat);
    k2_gemm1<<<dim3(1024), dim3(256), 0, stream>>>(Xb, WL, WR, P16);
    k3_astats<<<dim3(512), dim3(256), 0, stream>>>(P16, Ab, astat);
    k4_gemm2<<<dim3(1888), dim3(256), 0, stream>>>(Ab, Xb, astat, xstat, C);
}